// Round 1
// 300.731 us; speedup vs baseline: 1.0562x; 1.0562x over previous
//
#include <hip/hip_runtime.h>

#define T_FRAMES 32768
#define ROWF 1629          // 543*3 floats per frame
#define NSEG 512
#define NVAL 122           // 42 hand + 80 lips values per frame
#define PADI 16            // accumulator padding: one per 64B cacheline

// -------------------------------------------------------------------------
// K1: keep flags only. One frame per wave; reads ONLY the hand region
// (~750 B/frame -> ~25 MB total vs 213 MB before). keep==0 iff all hand
// entries NaN (contributions are nonnegative, 1-y>0 when finite).
// -------------------------------------------------------------------------
__global__ __launch_bounds__(256) void k1_keep(const float* __restrict__ frames,
                                               int* __restrict__ keep) {
  int lane = threadIdx.x & 63;
  int wid = threadIdx.x >> 6;                 // 0..3
  int t = blockIdx.x * 4 + wid;
  const float* f = frames + (size_t)t * ROWF;
  float s = 0.0f;
  if (lane < 42) {
    int j = (lane < 21) ? lane : lane - 21;
    int base = ((lane < 21) ? 468 : 522) + j;
    float x = f[base * 3];
    float y = f[base * 3 + 1];
    float ax = (lane < 21) ? x : 1.0f - x;    // lh:[x,1-y]  rh:[1-x,1-y]
    float ay = 1.0f - y;
    ax = (ax == ax) ? ax : 0.0f;
    ay = (ay == ay) ? ay : 0.0f;
    s = ax + ay;
  }
  #pragma unroll
  for (int off = 32; off > 0; off >>= 1) s += __shfl_down(s, off);
  if (lane == 0) keep[t] = (s != 0.0f) ? 1 : 0;
}

// -------------------------------------------------------------------------
// K2: single-block prefix scan of keep[] -> compacted kept_t[], total S.
// (unchanged from verified kernel)
// -------------------------------------------------------------------------
__global__ __launch_bounds__(1024) void k2_scan(const int* __restrict__ keep,
                                                int* __restrict__ kept_t,
                                                int* __restrict__ Sp) {
  __shared__ int wsum[16];
  int tid = threadIdx.x;
  const int PER = T_FRAMES / 1024;            // 32
  int base = tid * PER;
  int fl[PER];
  int local = 0;
  #pragma unroll
  for (int k = 0; k < PER; ++k) { fl[k] = keep[base + k]; local += fl[k]; }

  int lane = tid & 63, wid = tid >> 6;
  int scan = local;
  #pragma unroll
  for (int off = 1; off < 64; off <<= 1) {
    int n = __shfl_up(scan, off);
    if (lane >= off) scan += n;
  }
  if (lane == 63) wsum[wid] = scan;
  __syncthreads();
  if (tid < 16) {
    int v = wsum[tid];
    #pragma unroll
    for (int off = 1; off < 16; off <<= 1) {
      int n = __shfl_up(v, off);
      if (tid >= off) v += n;
    }
    wsum[tid] = v;
  }
  __syncthreads();
  int excl = ((wid == 0) ? 0 : wsum[wid - 1]) + (scan - local);
  #pragma unroll
  for (int k = 0; k < PER; ++k) {
    if (fl[k]) kept_t[excl++] = base + k;
  }
  if (tid == 1023) Sp[0] = wsum[15];
}

// -------------------------------------------------------------------------
// K3: one block (1024 thr = 16 waves) per segment. The block exclusively
// owns kept ranks [lo,hi), so segment accumulation needs NO global atomics.
// Single gather pass over frames; per-wave register accumulation; LDS
// reduce; hand means written directly. Lips finite-sums/counts stored
// per-segment plus 160 padded atomics/block into the global totals (for cm).
// Lane roles per frame: [0,21) lh-pair j=lane; [21,42) rh-pair j=lane-21;
// [42,64) lips-pair j=lane-42; second set: lane<18 lips-pair j=22+lane.
// -------------------------------------------------------------------------
__global__ __launch_bounds__(1024) void k3_seg(
    const float* __restrict__ frames, const int* __restrict__ lips_idx,
    const int* __restrict__ kept_t, const int* __restrict__ Sp,
    float* __restrict__ out, int out_size,
    float* __restrict__ seg_ls, int* __restrict__ seg_lc,
    int* __restrict__ seg_n, float* __restrict__ tot_s,
    int* __restrict__ tot_c) {
  __shared__ int seglist[72];                 // cnt <= ceil((S-1)/512) <= 64
  __shared__ float h_s[42];
  __shared__ float l_s[80];
  __shared__ int   l_c[80];
  int tid = threadIdx.x, lane = tid & 63, wid = tid >> 6;
  int seg = blockIdx.x;
  int S = Sp[0];
  long long M = (long long)S - 1; if (M < 0) M = 0;
  int lo = (int)(((long long)seg * M) >> 9);
  int hi = (int)(((long long)(seg + 1) * M) >> 9);
  int cnt = hi - lo;
  // rank S-1 is in no segment (JAX OOB-drop) but IS in the lips column mean
  int loadN = cnt + ((seg == NSEG - 1 && S >= 2) ? 1 : 0);

  if (tid < 42) h_s[tid] = 0.0f;
  if (tid < 80) { l_s[tid] = 0.0f; l_c[tid] = 0; }
  if (tid < loadN) seglist[tid] = kept_t[lo + tid];
  __syncthreads();

  int idx1 = 0, idx2 = 0;
  if (lane >= 42) idx1 = lips_idx[lane - 42];
  if (lane < 18)  idx2 = lips_idx[22 + lane];

  float ahx = 0.0f, ahy = 0.0f;               // hand acc (lane<21)
  float a1x = 0.0f, a1y = 0.0f; int c1x = 0, c1y = 0;  // lips set1 (lane>=42)
  float a2x = 0.0f, a2y = 0.0f; int c2x = 0, c2y = 0;  // lips set2 (lane<18)

  for (int k = wid; k < cnt; k += 16) {
    const float* f = frames + (size_t)seglist[k] * ROWF;
    int o1;
    if (lane < 21)      o1 = (468 + lane) * 3;
    else if (lane < 42) o1 = (522 + (lane - 21)) * 3;
    else                o1 = idx1 * 3;
    float x1 = f[o1], y1 = f[o1 + 1];
    float x2 = 0.0f, y2 = 0.0f;
    if (lane < 18) { int o2 = idx2 * 3; x2 = f[o2]; y2 = f[o2 + 1]; }

    // hand transform (lanes<42): lh -> (x,1-y), rh -> (1-x,1-y), nan->0
    float ax = (lane < 21) ? x1 : 1.0f - x1;
    float ay = 1.0f - y1;
    ax = (ax == ax) ? ax : 0.0f;
    ay = (ay == ay) ? ay : 0.0f;
    float bx = __shfl(ax, lane + 21);         // lane j pulls rh pair j
    float by = __shfl(ay, lane + 21);
    if (lane < 21) { ahx += ax + bx; ahy += ay + by; }
    if (lane >= 42) {
      if (x1 == x1) { a1x += x1; c1x++; }
      if (y1 == y1) { a1y += y1; c1y++; }
    }
    if (lane < 18) {
      if (x2 == x2) { a2x += x2; c2x++; }
      if (y2 == y2) { a2y += y2; c2y++; }
    }
  }

  // block reduce: 16 waves into LDS (16-way atomic contention max)
  if (lane < 21) { atomicAdd(&h_s[2 * lane], ahx); atomicAdd(&h_s[2 * lane + 1], ahy); }
  if (lane >= 42) {
    int j = lane - 42;
    atomicAdd(&l_s[2 * j], a1x); atomicAdd(&l_s[2 * j + 1], a1y);
    atomicAdd(&l_c[2 * j], c1x); atomicAdd(&l_c[2 * j + 1], c1y);
  }
  if (lane < 18) {
    int j = 22 + lane;
    atomicAdd(&l_s[2 * j], a2x); atomicAdd(&l_s[2 * j + 1], a2y);
    atomicAdd(&l_c[2 * j], c2x); atomicAdd(&l_c[2 * j + 1], c2y);
  }
  __syncthreads();

  if (tid < 42) {
    float v = cnt ? h_s[tid] / (float)cnt : 0.0f;
    int o = seg * NVAL + tid;
    if (o < out_size) out[o] = v;             // hand means final here
  }
  if (tid < 80) {
    seg_ls[seg * 80 + tid] = l_s[tid];
    seg_lc[seg * 80 + tid] = l_c[tid];
    atomicAdd(&tot_s[tid * PADI], l_s[tid]);  // padded: 1 accum / cacheline
    atomicAdd(&tot_c[tid * PADI], l_c[tid]);
  }
  if (tid == 0) seg_n[seg] = cnt;

  // rank S-1 -> global lips totals only
  if (seg == NSEG - 1 && S >= 2 && wid == 0 && lane < 40) {
    const float* f = frames + (size_t)seglist[cnt] * ROWF;
    int idx = lips_idx[lane];
    float x = f[idx * 3], y = f[idx * 3 + 1];
    if (x == x) { atomicAdd(&tot_s[(2 * lane) * PADI], x);
                  atomicAdd(&tot_c[(2 * lane) * PADI], 1); }
    if (y == y) { atomicAdd(&tot_s[(2 * lane + 1) * PADI], y);
                  atomicAdd(&tot_c[(2 * lane + 1) * PADI], 1); }
  }
}

// -------------------------------------------------------------------------
// K4: lips finalize. mean = (sum_finite + (n - c_finite)*cm) / n.
// -------------------------------------------------------------------------
__global__ __launch_bounds__(128) void k4_final(
    const float* __restrict__ seg_ls, const int* __restrict__ seg_lc,
    const int* __restrict__ seg_n, const float* __restrict__ tot_s,
    const int* __restrict__ tot_c, float* __restrict__ out, int out_size) {
  int w = threadIdx.x;
  int seg = blockIdx.x;
  if (w >= 80) return;
  int tc = tot_c[w * PADI];
  float cm = tc ? tot_s[w * PADI] / (float)tc : 0.0f;
  int n = seg_n[seg];
  float v = 0.0f;
  if (n) {
    int c = seg_lc[seg * 80 + w];
    v = (seg_ls[seg * 80 + w] + (float)(n - c) * cm) / (float)n;
  }
  int o = seg * NVAL + 42 + w;
  if (o < out_size) out[o] = v;
}

// -------------------------------------------------------------------------
extern "C" void kernel_launch(void* const* d_in, const int* in_sizes, int n_in,
                              void* d_out, int out_size, void* d_ws, size_t ws_size,
                              hipStream_t stream) {
  const float* frames = (const float*)d_in[0];
  const int* lips_idx = (const int*)d_in[1];
  float* out = (float*)d_out;

  char* ws = (char*)d_ws;
  int* keep      = (int*)(ws);                     // 131072 B
  int* kept_t    = (int*)(ws + 131072);            // 131072 B
  int* Sp        = (int*)(ws + 262144);            // 64 B
  float* tot_s   = (float*)(ws + 262208);          // 80 * 64B = 5120 B
  int* tot_c     = (int*)(ws + 267328);            // 80 * 64B = 5120 B
  float* seg_ls  = (float*)(ws + 272448);          // 512*80*4 = 163840 B
  int* seg_lc    = (int*)(ws + 436288);            // 163840 B
  int* seg_n     = (int*)(ws + 600128);            // 2048 B

  // totals must start at zero (ws is poisoned before every call);
  // tot_s/tot_c are contiguous -> one 10 KiB memset
  hipMemsetAsync((void*)tot_s, 0, 10240, stream);

  k1_keep<<<8192, 256, 0, stream>>>(frames, keep);
  k2_scan<<<1, 1024, 0, stream>>>(keep, kept_t, Sp);
  k3_seg<<<NSEG, 1024, 0, stream>>>(frames, lips_idx, kept_t, Sp, out, out_size,
                                    seg_ls, seg_lc, seg_n, tot_s, tot_c);
  k4_final<<<NSEG, 128, 0, stream>>>(seg_ls, seg_lc, seg_n, tot_s, tot_c,
                                     out, out_size);
}